// Round 12
// baseline (330.333 us; speedup 1.0000x reference)
//
#include <hip/hip_runtime.h>
#include <math.h>

// Problem constants
#define B8   8
#define HW4  196   // 14*14
#define HW5  49    // 7*7
#define HFW  28
#define NPIX 784   // 28*28
#define CAPP 1536
#define D1   38400 // 1536*25
#define NR   64    // B*G

typedef short short8 __attribute__((ext_vector_type(8)));
typedef short short4v __attribute__((ext_vector_type(4)));
typedef float floatx16 __attribute__((ext_vector_type(16)));

__device__ __forceinline__ unsigned short f2bf(float f) {
  unsigned u = __float_as_uint(f);
  u += 0x7FFF + ((u >> 16) & 1);
  return (unsigned short)(u >> 16);
}

struct Params {
  const float *x4, *x5, *boxes, *skel;
  const int *group, *label;
  const float *c1w, *c1b, *w2c, *b2c, *w3c, *b3c;
  const float *n1w, *n1b, *n2w, *n2b, *fw1, *fb1, *fw2, *fb2;
  float* out;
  unsigned short *x4T, *x5T, *sknT, *w2cH, *w3cH;
  float *f4T, *f5T, *tap4w, *tap5w, *descw, *roisP, *stats, *out1;
  int *tap4o, *tap5o, *desco, *cnt;
};

// Per-phase dedicated shared memory. launch_bounds stays (256,4): R6 proved
// the 2nd arg caps the register allocator ((256,8) -> VGPR 32 -> spills).
struct Sh0 { float tile[6432]; };                         // 25.7 KB
struct GemmSh {                                           // 16 KB (single buf)
  unsigned short As[4096];                                // [ko*512 + (m^ko)*8]
  unsigned short Bs[4096];                                // [ko*512 + (n^ko)*8]
};
struct Sh2 {
  float cw4[16], cw5[16], wgs;
  int co4[16], co5[16];
  float red[8];
  int lastf;
};                                                        // ~200 B
struct Sh5 { float red[8]; float red2[24]; };             // 128 B

// ---- one 64m x 64n GEMM tile: C[m][n] (+)= sum_{k0..k0+kchunk} A[m][k]*W[n][k] ----
// A bf16 k-contig rows. B bf16 pre-converted (BHALF) or fp32 (fw1, read once).
template <bool BHALF>
__device__ __forceinline__ void gemm_unit(
    GemmSh& sh, const unsigned short* __restrict__ A, const void* __restrict__ Bw,
    float* __restrict__ C, int mt, int nt, int k0, int kchunk,
    int K, int N, int Mvalid, bool accum) {
  int t = threadIdx.x;
  int wave = t >> 6, lane = t & 63;
  int wm = wave & 1, wn = wave >> 1;
  const unsigned short* Aptr = A + (size_t)(mt * 64) * K + k0;
  const unsigned short* Bph = (const unsigned short*)Bw + (size_t)(nt * 64) * K + k0;
  const float* Bpf = (const float*)Bw + (size_t)(nt * 64) * K + k0;

  int m0 = t >> 3, ka = (t & 7) * 8, koa = t & 7;
  int n0 = t >> 4, kbo = (t & 15) * 4, kob = (t & 15) >> 1, half = t & 1;

  short8 areg[2];
  short8 bregh[2];
  float4 breg[4];
  floatx16 acc;
#pragma unroll
  for (int i = 0; i < 16; i++) acc[i] = 0.f;
  int nkb = kchunk >> 6;

  auto LOAD = [&](int j) {
    int kof = j * 64;
    areg[0] = *(const short8*)(Aptr + (size_t)m0 * K + kof + ka);
    areg[1] = *(const short8*)(Aptr + (size_t)(m0 + 32) * K + kof + ka);
    if constexpr (BHALF) {
      bregh[0] = *(const short8*)(Bph + (size_t)m0 * K + kof + ka);
      bregh[1] = *(const short8*)(Bph + (size_t)(m0 + 32) * K + kof + ka);
    } else {
#pragma unroll
      for (int i = 0; i < 4; i++)
        breg[i] = *(const float4*)(Bpf + (size_t)(n0 + 16 * i) * K + kof + kbo);
    }
  };
  auto STORE = [&]() {
    *(short8*)&sh.As[koa * 512 + ((m0 ^ koa)) * 8] = areg[0];
    *(short8*)&sh.As[koa * 512 + (((m0 + 32) ^ koa)) * 8] = areg[1];
    if constexpr (BHALF) {
      *(short8*)&sh.Bs[koa * 512 + ((m0 ^ koa)) * 8] = bregh[0];
      *(short8*)&sh.Bs[koa * 512 + (((m0 + 32) ^ koa)) * 8] = bregh[1];
    } else {
#pragma unroll
      for (int i = 0; i < 4; i++) {
        short4v v;
        v[0] = (short)f2bf(breg[i].x); v[1] = (short)f2bf(breg[i].y);
        v[2] = (short)f2bf(breg[i].z); v[3] = (short)f2bf(breg[i].w);
        int n = n0 + 16 * i;
        *(short4v*)&sh.Bs[kob * 512 + ((n ^ kob)) * 8 + half * 4] = v;
      }
    }
  };

  // prologue: tile 0 staged
  LOAD(0);
  STORE();
  __syncthreads();

  for (int kb = 0; kb < nkb; kb++) {
    bool more = (kb + 1) < nkb;
    if (more) LOAD(kb + 1);            // regs for next tile in flight
#pragma unroll
    for (int s = 0; s < 4; s++) {
      int ko = 2 * s + (lane >> 5);
      int am = wm * 32 + (lane & 31);
      int bn = wn * 32 + (lane & 31);
      short8 af = *(const short8*)&sh.As[ko * 512 + ((am ^ ko)) * 8];
      short8 bf = *(const short8*)&sh.Bs[ko * 512 + ((bn ^ ko)) * 8];
      acc = __builtin_amdgcn_mfma_f32_32x32x16_bf16(af, bf, acc, 0, 0, 0);
    }
    __syncthreads();
    if (more) {
      STORE();
      __syncthreads();
    }
  }

  // C/D layout (m74/m101): col=lane&31, row=(reg&3)+8*(reg>>2)+4*(lane>>5)
  int col = nt * 64 + wn * 32 + (lane & 31);
  int rbase = mt * 64 + wm * 32 + 4 * (lane >> 5);
  if (accum) {
#pragma unroll
    for (int reg = 0; reg < 16; reg++) {
      int row = rbase + (reg & 3) + 8 * (reg >> 2);
      if (row < Mvalid) atomicAdd(&C[(size_t)row * N + col], acc[reg]);
    }
  } else {
#pragma unroll
    for (int reg = 0; reg < 16; reg++) {
      int row = rbase + (reg & 3) + 8 * (reg >> 2);
      if (row < Mvalid) C[(size_t)row * N + col] = acc[reg];
    }
  }
}

__device__ __forceinline__ float gate_val(const float* sk, int yy, int xx,
                                          float c1w, float c1b, bool use) {
  if (!use) return 1.f;
  float z = sk[yy * HFW + xx] * c1w + c1b;
  return 1.f / (1.f + expf(-z));
}

// =============== phase kernels =================
__global__ __launch_bounds__(256, 4) void k_phase0(Params p) {
  __shared__ Sh0 sh;
  int bid = blockIdx.x, t = threadIdx.x, gb = gridDim.x;
  int gtid = bid * 256 + t;
  int nth = gb * 256;
  // zero accumulated buffers: f4T+f5T contiguous + out1 + stats + cnt
  float4 z4 = make_float4(0.f, 0.f, 0.f, 0.f);
  for (int i = gtid; i < 319488; i += nth) ((float4*)p.f4T)[i] = z4;
  for (int i = gtid; i < 8192; i += nth) ((float4*)p.out1)[i] = z4;
  if (gtid < 128) p.stats[gtid] = 0.f;
  if (gtid < 64) p.cnt[gtid] = 0;
  // pre-convert conv weights to bf16 (read 25x/7x in phase1 -> halves B bytes)
  for (int i = gtid; i < 131072; i += nth) {
    float4 v = ((const float4*)p.w2c)[i];
    short4v h;
    h[0] = (short)f2bf(v.x); h[1] = (short)f2bf(v.y);
    h[2] = (short)f2bf(v.z); h[3] = (short)f2bf(v.w);
    *(short4v*)&p.w2cH[i * 4] = h;
  }
  for (int i = gtid; i < 524288; i += nth) {
    float4 v = ((const float4*)p.w3c)[i];
    short4v h;
    h[0] = (short)f2bf(v.x); h[1] = (short)f2bf(v.y);
    h[2] = (short)f2bf(v.z); h[3] = (short)f2bf(v.w);
    *(short4v*)&p.w3cH[i * 4] = h;
  }

  for (int u = bid; u < 836; u += gb) {
    __syncthreads();
    if (u < 256) {
      int b = u >> 5, cc = u & 31;
      for (int i = t; i < 32 * HW4; i += 256) {
        int c = i / HW4, hw = i - c * HW4;
        sh.tile[c * 201 + hw] = p.x4[((size_t)(b * 1024 + cc * 32 + c)) * HW4 + hw];
      }
      __syncthreads();
      // 4 channels/thread -> short4 (8B) stores, 4x fewer store instrs.
      for (int i = t; i < HW4 * 8; i += 256) {
        int hw = i >> 3, c4 = (i & 7) * 4;
        short4v h;
#pragma unroll
        for (int q = 0; q < 4; q++) h[q] = (short)f2bf(sh.tile[(c4 + q) * 201 + hw]);
        *(short4v*)&p.x4T[((size_t)(b * HW4 + hw)) * 1024 + cc * 32 + c4] = h;
      }
    } else if (u < 768) {
      int u2 = u - 256;
      int b = u2 >> 6, cc = u2 & 63;
      for (int i = t; i < 32 * HW5; i += 256) {
        int c = i / HW5, hw = i - c * HW5;
        sh.tile[c * 51 + hw] = p.x5[((size_t)(b * 2048 + cc * 32 + c)) * HW5 + hw];
      }
      __syncthreads();
      for (int i = t; i < HW5 * 8; i += 256) {
        int hw = i >> 3, c4 = (i & 7) * 4;
        short4v h;
#pragma unroll
        for (int q = 0; q < 4; q++) h[q] = (short)f2bf(sh.tile[(c4 + q) * 51 + hw]);
        *(short4v*)&p.x5T[((size_t)(b * HW5 + hw)) * 2048 + cc * 32 + c4] = h;
      }
    } else if (u < 832) {
      int bg = u - 768;
      if (t < 25) {
        int b = bg >> 3;
        int i1 = p.group[bg * 2 + 0], i2 = p.group[bg * 2 + 1];
        const float* bb1 = p.boxes + (size_t)(b * 16 + i1) * 4;
        const float* bb2 = p.boxes + (size_t)(b * 16 + i2) * 4;
        float ux1 = fminf(bb1[0], bb2[0]);
        float uy1 = fminf(bb1[1], bb2[1]);
        float ux2 = fmaxf(bb1[2], bb2[2]);
        float uy2 = fmaxf(bb1[3], bb2[3]);
        float rw = fmaxf(ux2 - ux1, 1.0f), rh = fmaxf(uy2 - uy1, 1.0f);
        int iy = t / 5, ix = t % 5;
        float sy = uy1 + (iy + 0.5f) * (rh * 0.2f);
        float sx = ux1 + (ix + 0.5f) * (rw * 0.2f);
        float valid = (sy >= -1.0f && sy <= 28.0f && sx >= -1.0f && sx <= 28.0f) ? 1.f : 0.f;
        float y = fminf(fmaxf(sy, 0.f), 27.f);
        float x = fminf(fmaxf(sx, 0.f), 27.f);
        int y0 = (int)floorf(y), x0 = (int)floorf(x);
        int y1 = min(y0 + 1, 27), x1 = min(x0 + 1, 27);
        float ly = y - (float)y0, lx = x - (float)x0;
        bool use = (p.label[bg] != -1);
        float c1w = p.c1w[0], c1b = p.c1b[0];
        const float* sk = p.skel + (size_t)bg * NPIX;
        int idx = (bg * 25 + t) * 4;
        p.descw[idx + 0] = (1.f - ly) * (1.f - lx) * valid * gate_val(sk, y0, x0, c1w, c1b, use);
        p.descw[idx + 1] = (1.f - ly) * lx * valid * gate_val(sk, y0, x1, c1w, c1b, use);
        p.descw[idx + 2] = ly * (1.f - lx) * valid * gate_val(sk, y1, x0, c1w, c1b, use);
        p.descw[idx + 3] = ly * lx * valid * gate_val(sk, y1, x1, c1w, c1b, use);
        p.desco[idx + 0] = y0 * HFW + x0;
        p.desco[idx + 1] = y0 * HFW + x1;
        p.desco[idx + 2] = y1 * HFW + x0;
        p.desco[idx + 3] = y1 * HFW + x1;
      }
    } else {
      int pix = (u - 832) * 196 + t;
      if (t < 196) {
        int y = pix / HFW, x = pix % HFW;
        {
          float sy = y * (13.0f / 27.0f), sx = x * (13.0f / 27.0f);
          int y0 = (int)sy, x0 = (int)sx;
          int y1 = min(y0 + 1, 13), x1 = min(x0 + 1, 13);
          float ly = sy - y0, lx = sx - x0;
          p.tap4o[pix * 4 + 0] = y0 * 14 + x0; p.tap4w[pix * 4 + 0] = (1.f - ly) * (1.f - lx);
          p.tap4o[pix * 4 + 1] = y0 * 14 + x1; p.tap4w[pix * 4 + 1] = (1.f - ly) * lx;
          p.tap4o[pix * 4 + 2] = y1 * 14 + x0; p.tap4w[pix * 4 + 2] = ly * (1.f - lx);
          p.tap4o[pix * 4 + 3] = y1 * 14 + x1; p.tap4w[pix * 4 + 3] = ly * lx;
        }
        {
          float sy = y * (6.0f / 27.0f), sx = x * (6.0f / 27.0f);
          int y0 = (int)sy, x0 = (int)sx;
          int y1 = min(y0 + 1, 6), x1 = min(x0 + 1, 6);
          float ly = sy - y0, lx = sx - x0;
          p.tap5o[pix * 4 + 0] = y0 * 7 + x0; p.tap5w[pix * 4 + 0] = (1.f - ly) * (1.f - lx);
          p.tap5o[pix * 4 + 1] = y0 * 7 + x1; p.tap5w[pix * 4 + 1] = (1.f - ly) * lx;
          p.tap5o[pix * 4 + 2] = y1 * 7 + x0; p.tap5w[pix * 4 + 2] = ly * (1.f - lx);
          p.tap5o[pix * 4 + 3] = y1 * 7 + x1; p.tap5w[pix * 4 + 3] = ly * lx;
        }
      }
    }
  }
}

__global__ __launch_bounds__(256, 4) void k_phase1(Params p) {
  // conv4 800 units + conv5 896 units, bf16 weights, XCD-chunked (1696=8*212).
  __shared__ GemmSh sh;
  int bid = blockIdx.x, gb = gridDim.x;
  for (int uu = bid; uu < 1696; uu += gb) {
    int u = (uu & 7) * 212 + (uu >> 3);
    __syncthreads();
    if (u < 800) {
      int mt = u % 25, r = u / 25;
      int nt = r & 7, sp = r >> 3;
      gemm_unit<true>(sh, p.x4T, p.w2cH, p.f4T, mt, nt, sp * 256, 256, 1024, 512, 1568, true);
    } else {
      int u2 = u - 800;
      int mt = u2 % 7, r = u2 / 7;
      int nt = r & 15, sp = r >> 4;
      gemm_unit<true>(sh, p.x5T, p.w3cH, p.f5T, mt, nt, sp * 256, 256, 2048, 1024, 392, true);
    }
  }
}

__global__ __launch_bounds__(256, 4) void k_phase2(Params p) {
  // XCD swizzle (1600 = 8*200): one batch per XCD -> f4T/f5T L2-resident,
  // AND all 25 pp-blocks of a row bg land on one XCD -> same-L2 completion.
  // R12: p3 fused in — the 25th (last) block of each row does the LN1 apply
  // + ReLU + bf16 store for the whole row (stats complete by then; roisP
  // chunks are local-L2-hot). Removes the p3 dispatch + its cold re-read.
  __shared__ Sh2 sh;
  int bid = blockIdx.x, t = threadIdx.x, gb = gridDim.x;
  for (int uu = bid; uu < 1600; uu += gb) {
    int u = (uu & 7) * 200 + (uu >> 3);
    __syncthreads();
    int pp = u % 25, bg = u / 25, b = bg >> 3;
    int di = (bg * 25 + pp) * 4;
    if (t < 16) {
      int i = t >> 2, j = t & 3;
      float wg = p.descw[di + i];
      int pix = p.desco[di + i];
      sh.cw4[t] = wg * p.tap4w[pix * 4 + j];
      sh.co4[t] = (b * HW4 + p.tap4o[pix * 4 + j]) * 512;
      sh.cw5[t] = wg * p.tap5w[pix * 4 + j];
      sh.co5[t] = (b * HW5 + p.tap5o[pix * 4 + j]) * 1024;
    }
    if (t == 16) sh.wgs = p.descw[di] + p.descw[di + 1] + p.descw[di + 2] + p.descw[di + 3];
    __syncthreads();
    float w4r[16], w5r[16];
    int o4r[16], o5r[16];
    float wg = sh.wgs;
#pragma unroll
    for (int i = 0; i < 16; i++) {
      w4r[i] = sh.cw4[i]; o4r[i] = sh.co4[i];
      w5r[i] = sh.cw5[i]; o5r[i] = sh.co5[i];
    }
    float ls = 0.f, ls2 = 0.f;
    float* outp = p.roisP + (size_t)(bg * 25 + pp) * CAPP;
    for (int c = t; c < 512; c += 256) {
      float acc = wg * p.b2c[c];
#pragma unroll
      for (int i = 0; i < 16; i++) acc = fmaf(w4r[i], p.f4T[o4r[i] + c], acc);
      outp[c] = acc;
      ls += acc; ls2 = fmaf(acc, acc, ls2);
    }
    for (int c = t; c < 1024; c += 256) {
      float acc = wg * p.b3c[c];
#pragma unroll
      for (int i = 0; i < 16; i++) acc = fmaf(w5r[i], p.f5T[o5r[i] + c], acc);
      outp[512 + c] = acc;
      ls += acc; ls2 = fmaf(acc, acc, ls2);
    }
    for (int off = 32; off; off >>= 1) {
      ls += __shfl_down(ls, off);
      ls2 += __shfl_down(ls2, off);
    }
    int wv = t >> 6;
    if ((t & 63) == 0) { sh.red[wv] = ls; sh.red[4 + wv] = ls2; }
    __syncthreads();
    if (t == 0) {
      atomicAdd(&p.stats[bg * 2 + 0], sh.red[0] + sh.red[1] + sh.red[2] + sh.red[3]);
      atomicAdd(&p.stats[bg * 2 + 1], sh.red[4] + sh.red[5] + sh.red[6] + sh.red[7]);
      // __syncthreads above drained all threads' roisP stores to L2 (compiler
      // emits s_waitcnt vmcnt(0) before s_barrier); fence orders the stats
      // atomic before the completion count.
      __threadfence();
      int old = atomicAdd(&p.cnt[bg], 1);
      sh.lastf = (old == 24) ? 1 : 0;
    }
    __syncthreads();
    if (sh.lastf) {
      // This block is the 25th finisher for row bg: stats are complete and
      // all 25 roisP chunks are resident in THIS XCD's L2 (swizzle property).
      float S = p.stats[bg * 2], S2 = p.stats[bg * 2 + 1];
      float mu = S * (1.f / D1);
      float var = S2 * (1.f / D1) - mu * mu;
      float rs = rsqrtf(var + 1e-5f);
      const float* rp = p.roisP + (size_t)bg * 25 * CAPP;
      unsigned short* op = p.sknT + (size_t)bg * D1;
      for (int k = t; k < D1; k += 256) {
        unsigned c = (unsigned)k / 25u;
        unsigned q = (unsigned)k - c * 25u;
        float x = rp[(size_t)q * CAPP + c];
        float v = fmaf((x - mu) * rs, p.n1w[k], p.n1b[k]);
        op[k] = f2bf(fmaxf(v, 0.f));
      }
    }
  }
}

__global__ __launch_bounds__(256, 4) void k_phase4(Params p) {
  // fc1: 8 ntiles x 120 k-splits of 320, atomic into out1 (best config).
  // XCD-chunked (960 = 8*120).
  __shared__ GemmSh sh;
  int bid = blockIdx.x, gb = gridDim.x;
  for (int uu = bid; uu < 960; uu += gb) {
    int u = (uu & 7) * 120 + (uu >> 3);
    __syncthreads();
    int nt = u & 7, sp = u >> 3;
    gemm_unit<false>(sh, p.sknT, p.fw1, p.out1, 0, nt, sp * 320, 320, 38400, 512, 64, true);
  }
}

__global__ __launch_bounds__(256, 4) void k_phase5(Params p) {
  // LN2 + fc2 from out1 (fc1 atomics) + fb1.
  __shared__ Sh5 sh;
  int bid = blockIdx.x, t = threadIdx.x, gb = gridDim.x;
  for (int r = bid; r < NR; r += gb) {
    __syncthreads();
    int j1 = t, j2 = t + 256;
    float v1 = p.out1[r * 512 + j1] + p.fb1[j1];
    float v2 = p.out1[r * 512 + j2] + p.fb1[j2];
    float s = v1 + v2, s2 = v1 * v1 + v2 * v2;
    for (int off = 32; off; off >>= 1) {
      s += __shfl_down(s, off);
      s2 += __shfl_down(s2, off);
    }
    int wv = t >> 6;
    if ((t & 63) == 0) { sh.red[wv] = s; sh.red[4 + wv] = s2; }
    __syncthreads();
    float S = sh.red[0] + sh.red[1] + sh.red[2] + sh.red[3];
    float S2 = sh.red[4] + sh.red[5] + sh.red[6] + sh.red[7];
    float mu = S / 512.f;
    float var = S2 / 512.f - mu * mu;
    float rs = rsqrtf(var + 1e-5f);
    float n1v = fmaf((v1 - mu) * rs, p.n2w[j1], p.n2b[j1]);
    float n2v = fmaf((v2 - mu) * rs, p.n2w[j2], p.n2b[j2]);
    float pm[6];
#pragma unroll
    for (int m = 0; m < 6; m++)
      pm[m] = n1v * p.fw2[m * 512 + j1] + n2v * p.fw2[m * 512 + j2];
#pragma unroll
    for (int m = 0; m < 6; m++)
      for (int off = 32; off; off >>= 1) pm[m] += __shfl_down(pm[m], off);
    if ((t & 63) == 0) {
#pragma unroll
      for (int m = 0; m < 6; m++) sh.red2[wv * 6 + m] = pm[m];
    }
    __syncthreads();
    if (t < 6)
      p.out[r * 6 + t] = sh.red2[t] + sh.red2[6 + t] + sh.red2[12 + t] +
                         sh.red2[18 + t] + p.fb2[t];
  }
}

extern "C" void kernel_launch(void* const* d_in, const int* in_sizes, int n_in,
                              void* d_out, int out_size, void* d_ws, size_t ws_size,
                              hipStream_t stream) {
  Params p;
  p.x4    = (const float*)d_in[0];
  p.x5    = (const float*)d_in[1];
  p.boxes = (const float*)d_in[2];
  p.skel  = (const float*)d_in[3];
  p.group = (const int*)d_in[4];
  p.label = (const int*)d_in[6];
  p.c1w   = (const float*)d_in[7];
  p.c1b   = (const float*)d_in[8];
  p.w2c   = (const float*)d_in[9];
  p.b2c   = (const float*)d_in[10];
  p.w3c   = (const float*)d_in[11];
  p.b3c   = (const float*)d_in[12];
  p.n1w   = (const float*)d_in[13];
  p.n1b   = (const float*)d_in[14];
  p.n2w   = (const float*)d_in[15];
  p.n2b   = (const float*)d_in[16];
  p.fw1   = (const float*)d_in[17];
  p.fb1   = (const float*)d_in[18];
  p.fw2   = (const float*)d_in[19];
  p.fb2   = (const float*)d_in[20];
  p.out   = (float*)d_out;

  // workspace layout — ALL offsets in FLOAT units.
  float* ws = (float*)d_ws;
  p.x4T   = (unsigned short*)ws;              // 1600*1024 sh = 819200 f
  p.x5T   = (unsigned short*)(ws + 819200);   // 448*2048 sh  = 458752 f
  p.f4T   = ws + 1277952;                     // 1600*512  = 819,200 (1568 valid)
  p.f5T   = ws + 2097152;                     // 448*1024  = 458,752 (392 valid)
  p.tap4w = ws + 2555904;                     // 3136
  p.tap4o = (int*)(ws + 2559040);             // 3136
  p.tap5w = ws + 2562176;                     // 3136
  p.tap5o = (int*)(ws + 2565312);             // 3136
  p.descw = ws + 2568448;                     // 6400
  p.desco = (int*)(ws + 2574848);             // 6400
  p.roisP = ws + 2581248;                     // 64*25*1536 = 2,457,600
  p.stats = ws + 5038848;                     // 128 (raw S, S2 per row)
  p.sknT  = (unsigned short*)(ws + 5038976);  // 64*38400 sh = 1,228,800 f
  p.out1  = ws + 6267776;                     // 64*512 = 32,768
  p.w2cH  = (unsigned short*)(ws + 6300544);  // 524,288 sh = 262,144 f
  p.w3cH  = (unsigned short*)(ws + 6562688);  // 2,097,152 sh = 1,048,576 f
  p.cnt   = (int*)(ws + 7611264);             // 64 ints (end 7,611,328 f)

  k_phase0<<<836,  256, 0, stream>>>(p);
  k_phase1<<<1696, 256, 0, stream>>>(p);
  k_phase2<<<1600, 256, 0, stream>>>(p);
  k_phase4<<<960,  256, 0, stream>>>(p);
  k_phase5<<<64,   256, 0, stream>>>(p);
}

// Round 13
// 235.358 us; speedup vs baseline: 1.4035x; 1.4035x over previous
//
#include <hip/hip_runtime.h>
#include <math.h>

// Problem constants
#define B8   8
#define HW4  196   // 14*14
#define HW5  49    // 7*7
#define HFW  28
#define NPIX 784   // 28*28
#define CAPP 1536
#define D1   38400 // 1536*25
#define NR   64    // B*G

typedef short short8 __attribute__((ext_vector_type(8)));
typedef short short4v __attribute__((ext_vector_type(4)));
typedef float floatx16 __attribute__((ext_vector_type(16)));

__device__ __forceinline__ unsigned short f2bf(float f) {
  unsigned u = __float_as_uint(f);
  u += 0x7FFF + ((u >> 16) & 1);
  return (unsigned short)(u >> 16);
}

struct Params {
  const float *x4, *x5, *boxes, *skel;
  const int *group, *label;
  const float *c1w, *c1b, *w2c, *b2c, *w3c, *b3c;
  const float *n1w, *n1b, *n2w, *n2b, *fw1, *fb1, *fw2, *fb2;
  float* out;
  unsigned short *x4T, *x5T, *sknT, *w2cH, *w3cH;
  float *f4T, *f5T, *tap4w, *tap5w, *descw, *roisP, *stats, *out1;
  int *tap4o, *tap5o, *desco;
};

// Per-phase dedicated shared memory. launch_bounds stays (256,4): R6 proved
// the 2nd arg caps the register allocator ((256,8) -> VGPR 32 -> spills).
struct Sh0 { float tile[6432]; };                         // 25.7 KB
struct GemmSh {                                           // 16 KB (single buf)
  unsigned short As[4096];                                // [ko*512 + (m^ko)*8]
  unsigned short Bs[4096];                                // [ko*512 + (n^ko)*8]
};
struct Sh2 {
  float cw4[16], cw5[16], wgs;
  int co4[16], co5[16];
  float red[8];
};                                                        // ~200 B
struct Sh3 { float tile[6424]; };                         // 25.7 KB
struct Sh5 { float red[8]; float red2[24]; };             // 128 B

// ---- one 64m x 64n GEMM tile: C[m][n] (+)= sum_{k0..k0+kchunk} A[m][k]*W[n][k] ----
// A bf16 k-contig rows. B bf16 pre-converted (BHALF) or fp32 (fw1, read once).
template <bool BHALF>
__device__ __forceinline__ void gemm_unit(
    GemmSh& sh, const unsigned short* __restrict__ A, const void* __restrict__ Bw,
    float* __restrict__ C, int mt, int nt, int k0, int kchunk,
    int K, int N, int Mvalid, bool accum) {
  int t = threadIdx.x;
  int wave = t >> 6, lane = t & 63;
  int wm = wave & 1, wn = wave >> 1;
  const unsigned short* Aptr = A + (size_t)(mt * 64) * K + k0;
  const unsigned short* Bph = (const unsigned short*)Bw + (size_t)(nt * 64) * K + k0;
  const float* Bpf = (const float*)Bw + (size_t)(nt * 64) * K + k0;

  int m0 = t >> 3, ka = (t & 7) * 8, koa = t & 7;
  int n0 = t >> 4, kbo = (t & 15) * 4, kob = (t & 15) >> 1, half = t & 1;

  short8 areg[2];
  short8 bregh[2];
  float4 breg[4];
  floatx16 acc;
#pragma unroll
  for (int i = 0; i < 16; i++) acc[i] = 0.f;
  int nkb = kchunk >> 6;

  auto LOAD = [&](int j) {
    int kof = j * 64;
    areg[0] = *(const short8*)(Aptr + (size_t)m0 * K + kof + ka);
    areg[1] = *(const short8*)(Aptr + (size_t)(m0 + 32) * K + kof + ka);
    if constexpr (BHALF) {
      bregh[0] = *(const short8*)(Bph + (size_t)m0 * K + kof + ka);
      bregh[1] = *(const short8*)(Bph + (size_t)(m0 + 32) * K + kof + ka);
    } else {
#pragma unroll
      for (int i = 0; i < 4; i++)
        breg[i] = *(const float4*)(Bpf + (size_t)(n0 + 16 * i) * K + kof + kbo);
    }
  };
  auto STORE = [&]() {
    *(short8*)&sh.As[koa * 512 + ((m0 ^ koa)) * 8] = areg[0];
    *(short8*)&sh.As[koa * 512 + (((m0 + 32) ^ koa)) * 8] = areg[1];
    if constexpr (BHALF) {
      *(short8*)&sh.Bs[koa * 512 + ((m0 ^ koa)) * 8] = bregh[0];
      *(short8*)&sh.Bs[koa * 512 + (((m0 + 32) ^ koa)) * 8] = bregh[1];
    } else {
#pragma unroll
      for (int i = 0; i < 4; i++) {
        short4v v;
        v[0] = (short)f2bf(breg[i].x); v[1] = (short)f2bf(breg[i].y);
        v[2] = (short)f2bf(breg[i].z); v[3] = (short)f2bf(breg[i].w);
        int n = n0 + 16 * i;
        *(short4v*)&sh.Bs[kob * 512 + ((n ^ kob)) * 8 + half * 4] = v;
      }
    }
  };

  // prologue: tile 0 staged
  LOAD(0);
  STORE();
  __syncthreads();

  for (int kb = 0; kb < nkb; kb++) {
    bool more = (kb + 1) < nkb;
    if (more) LOAD(kb + 1);            // regs for next tile in flight
#pragma unroll
    for (int s = 0; s < 4; s++) {
      int ko = 2 * s + (lane >> 5);
      int am = wm * 32 + (lane & 31);
      int bn = wn * 32 + (lane & 31);
      short8 af = *(const short8*)&sh.As[ko * 512 + ((am ^ ko)) * 8];
      short8 bf = *(const short8*)&sh.Bs[ko * 512 + ((bn ^ ko)) * 8];
      acc = __builtin_amdgcn_mfma_f32_32x32x16_bf16(af, bf, acc, 0, 0, 0);
    }
    __syncthreads();
    if (more) {
      STORE();
      __syncthreads();
    }
  }

  // C/D layout (m74/m101): col=lane&31, row=(reg&3)+8*(reg>>2)+4*(lane>>5)
  int col = nt * 64 + wn * 32 + (lane & 31);
  int rbase = mt * 64 + wm * 32 + 4 * (lane >> 5);
  if (accum) {
#pragma unroll
    for (int reg = 0; reg < 16; reg++) {
      int row = rbase + (reg & 3) + 8 * (reg >> 2);
      if (row < Mvalid) atomicAdd(&C[(size_t)row * N + col], acc[reg]);
    }
  } else {
#pragma unroll
    for (int reg = 0; reg < 16; reg++) {
      int row = rbase + (reg & 3) + 8 * (reg >> 2);
      if (row < Mvalid) C[(size_t)row * N + col] = acc[reg];
    }
  }
}

__device__ __forceinline__ float gate_val(const float* sk, int yy, int xx,
                                          float c1w, float c1b, bool use) {
  if (!use) return 1.f;
  float z = sk[yy * HFW + xx] * c1w + c1b;
  return 1.f / (1.f + expf(-z));
}

// =============== phase kernels =================
__global__ __launch_bounds__(256, 4) void k_phase0(Params p) {
  __shared__ Sh0 sh;
  int bid = blockIdx.x, t = threadIdx.x, gb = gridDim.x;
  int gtid = bid * 256 + t;
  int nth = gb * 256;
  // zero accumulated buffers: f4T+f5T contiguous + out1 + stats
  float4 z4 = make_float4(0.f, 0.f, 0.f, 0.f);
  for (int i = gtid; i < 319488; i += nth) ((float4*)p.f4T)[i] = z4;
  for (int i = gtid; i < 8192; i += nth) ((float4*)p.out1)[i] = z4;
  if (gtid < 128) p.stats[gtid] = 0.f;
  // pre-convert conv weights to bf16 (read 25x/7x in phase1 -> halves B bytes)
  for (int i = gtid; i < 131072; i += nth) {
    float4 v = ((const float4*)p.w2c)[i];
    short4v h;
    h[0] = (short)f2bf(v.x); h[1] = (short)f2bf(v.y);
    h[2] = (short)f2bf(v.z); h[3] = (short)f2bf(v.w);
    *(short4v*)&p.w2cH[i * 4] = h;
  }
  for (int i = gtid; i < 524288; i += nth) {
    float4 v = ((const float4*)p.w3c)[i];
    short4v h;
    h[0] = (short)f2bf(v.x); h[1] = (short)f2bf(v.y);
    h[2] = (short)f2bf(v.z); h[3] = (short)f2bf(v.w);
    *(short4v*)&p.w3cH[i * 4] = h;
  }

  for (int u = bid; u < 836; u += gb) {
    __syncthreads();
    if (u < 256) {
      int b = u >> 5, cc = u & 31;
      for (int i = t; i < 32 * HW4; i += 256) {
        int c = i / HW4, hw = i - c * HW4;
        sh.tile[c * 201 + hw] = p.x4[((size_t)(b * 1024 + cc * 32 + c)) * HW4 + hw];
      }
      __syncthreads();
      for (int i = t; i < HW4 * 32; i += 256) {
        int hw = i >> 5, c = i & 31;
        p.x4T[((size_t)(b * HW4 + hw)) * 1024 + cc * 32 + c] = f2bf(sh.tile[c * 201 + hw]);
      }
    } else if (u < 768) {
      int u2 = u - 256;
      int b = u2 >> 6, cc = u2 & 63;
      for (int i = t; i < 32 * HW5; i += 256) {
        int c = i / HW5, hw = i - c * HW5;
        sh.tile[c * 51 + hw] = p.x5[((size_t)(b * 2048 + cc * 32 + c)) * HW5 + hw];
      }
      __syncthreads();
      for (int i = t; i < HW5 * 32; i += 256) {
        int hw = i >> 5, c = i & 31;
        p.x5T[((size_t)(b * HW5 + hw)) * 2048 + cc * 32 + c] = f2bf(sh.tile[c * 51 + hw]);
      }
    } else if (u < 832) {
      int bg = u - 768;
      if (t < 25) {
        int b = bg >> 3;
        int i1 = p.group[bg * 2 + 0], i2 = p.group[bg * 2 + 1];
        const float* bb1 = p.boxes + (size_t)(b * 16 + i1) * 4;
        const float* bb2 = p.boxes + (size_t)(b * 16 + i2) * 4;
        float ux1 = fminf(bb1[0], bb2[0]);
        float uy1 = fminf(bb1[1], bb2[1]);
        float ux2 = fmaxf(bb1[2], bb2[2]);
        float uy2 = fmaxf(bb1[3], bb2[3]);
        float rw = fmaxf(ux2 - ux1, 1.0f), rh = fmaxf(uy2 - uy1, 1.0f);
        int iy = t / 5, ix = t % 5;
        float sy = uy1 + (iy + 0.5f) * (rh * 0.2f);
        float sx = ux1 + (ix + 0.5f) * (rw * 0.2f);
        float valid = (sy >= -1.0f && sy <= 28.0f && sx >= -1.0f && sx <= 28.0f) ? 1.f : 0.f;
        float y = fminf(fmaxf(sy, 0.f), 27.f);
        float x = fminf(fmaxf(sx, 0.f), 27.f);
        int y0 = (int)floorf(y), x0 = (int)floorf(x);
        int y1 = min(y0 + 1, 27), x1 = min(x0 + 1, 27);
        float ly = y - (float)y0, lx = x - (float)x0;
        bool use = (p.label[bg] != -1);
        float c1w = p.c1w[0], c1b = p.c1b[0];
        const float* sk = p.skel + (size_t)bg * NPIX;
        int idx = (bg * 25 + t) * 4;
        p.descw[idx + 0] = (1.f - ly) * (1.f - lx) * valid * gate_val(sk, y0, x0, c1w, c1b, use);
        p.descw[idx + 1] = (1.f - ly) * lx * valid * gate_val(sk, y0, x1, c1w, c1b, use);
        p.descw[idx + 2] = ly * (1.f - lx) * valid * gate_val(sk, y1, x0, c1w, c1b, use);
        p.descw[idx + 3] = ly * lx * valid * gate_val(sk, y1, x1, c1w, c1b, use);
        p.desco[idx + 0] = y0 * HFW + x0;
        p.desco[idx + 1] = y0 * HFW + x1;
        p.desco[idx + 2] = y1 * HFW + x0;
        p.desco[idx + 3] = y1 * HFW + x1;
      }
    } else {
      int pix = (u - 832) * 196 + t;
      if (t < 196) {
        int y = pix / HFW, x = pix % HFW;
        {
          float sy = y * (13.0f / 27.0f), sx = x * (13.0f / 27.0f);
          int y0 = (int)sy, x0 = (int)sx;
          int y1 = min(y0 + 1, 13), x1 = min(x0 + 1, 13);
          float ly = sy - y0, lx = sx - x0;
          p.tap4o[pix * 4 + 0] = y0 * 14 + x0; p.tap4w[pix * 4 + 0] = (1.f - ly) * (1.f - lx);
          p.tap4o[pix * 4 + 1] = y0 * 14 + x1; p.tap4w[pix * 4 + 1] = (1.f - ly) * lx;
          p.tap4o[pix * 4 + 2] = y1 * 14 + x0; p.tap4w[pix * 4 + 2] = ly * (1.f - lx);
          p.tap4o[pix * 4 + 3] = y1 * 14 + x1; p.tap4w[pix * 4 + 3] = ly * lx;
        }
        {
          float sy = y * (6.0f / 27.0f), sx = x * (6.0f / 27.0f);
          int y0 = (int)sy, x0 = (int)sx;
          int y1 = min(y0 + 1, 6), x1 = min(x0 + 1, 6);
          float ly = sy - y0, lx = sx - x0;
          p.tap5o[pix * 4 + 0] = y0 * 7 + x0; p.tap5w[pix * 4 + 0] = (1.f - ly) * (1.f - lx);
          p.tap5o[pix * 4 + 1] = y0 * 7 + x1; p.tap5w[pix * 4 + 1] = (1.f - ly) * lx;
          p.tap5o[pix * 4 + 2] = y1 * 7 + x0; p.tap5w[pix * 4 + 2] = ly * (1.f - lx);
          p.tap5o[pix * 4 + 3] = y1 * 7 + x1; p.tap5w[pix * 4 + 3] = ly * lx;
        }
      }
    }
  }
}

__global__ __launch_bounds__(256, 4) void k_phase1(Params p) {
  // conv4 800 units + conv5 896 units, bf16 weights, XCD-chunked (1696=8*212).
  __shared__ GemmSh sh;
  int bid = blockIdx.x, gb = gridDim.x;
  for (int uu = bid; uu < 1696; uu += gb) {
    int u = (uu & 7) * 212 + (uu >> 3);
    __syncthreads();
    if (u < 800) {
      int mt = u % 25, r = u / 25;
      int nt = r & 7, sp = r >> 3;
      gemm_unit<true>(sh, p.x4T, p.w2cH, p.f4T, mt, nt, sp * 256, 256, 1024, 512, 1568, true);
    } else {
      int u2 = u - 800;
      int mt = u2 % 7, r = u2 / 7;
      int nt = r & 15, sp = r >> 4;
      gemm_unit<true>(sh, p.x5T, p.w3cH, p.f5T, mt, nt, sp * 256, 256, 2048, 1024, 392, true);
    }
  }
}

__global__ __launch_bounds__(256, 4) void k_phase2(Params p) {
  // XCD swizzle (1600 = 8*200): one batch per XCD -> f4T/f5T L2-resident.
  // Scalar gathers with 16-deep load ILP (R9's float4 rewrite regressed;
  // R12's fused-LN tail regressed: 64-block straggler tail, 125us).
  __shared__ Sh2 sh;
  int bid = blockIdx.x, t = threadIdx.x, gb = gridDim.x;
  for (int uu = bid; uu < 1600; uu += gb) {
    int u = (uu & 7) * 200 + (uu >> 3);
    __syncthreads();
    int pp = u % 25, bg = u / 25, b = bg >> 3;
    int di = (bg * 25 + pp) * 4;
    if (t < 16) {
      int i = t >> 2, j = t & 3;
      float wg = p.descw[di + i];
      int pix = p.desco[di + i];
      sh.cw4[t] = wg * p.tap4w[pix * 4 + j];
      sh.co4[t] = (b * HW4 + p.tap4o[pix * 4 + j]) * 512;
      sh.cw5[t] = wg * p.tap5w[pix * 4 + j];
      sh.co5[t] = (b * HW5 + p.tap5o[pix * 4 + j]) * 1024;
    }
    if (t == 16) sh.wgs = p.descw[di] + p.descw[di + 1] + p.descw[di + 2] + p.descw[di + 3];
    __syncthreads();
    float w4r[16], w5r[16];
    int o4r[16], o5r[16];
    float wg = sh.wgs;
#pragma unroll
    for (int i = 0; i < 16; i++) {
      w4r[i] = sh.cw4[i]; o4r[i] = sh.co4[i];
      w5r[i] = sh.cw5[i]; o5r[i] = sh.co5[i];
    }
    float ls = 0.f, ls2 = 0.f;
    float* outp = p.roisP + (size_t)(bg * 25 + pp) * CAPP;
    for (int c = t; c < 512; c += 256) {
      float acc = wg * p.b2c[c];
#pragma unroll
      for (int i = 0; i < 16; i++) acc = fmaf(w4r[i], p.f4T[o4r[i] + c], acc);
      outp[c] = acc;
      ls += acc; ls2 = fmaf(acc, acc, ls2);
    }
    for (int c = t; c < 1024; c += 256) {
      float acc = wg * p.b3c[c];
#pragma unroll
      for (int i = 0; i < 16; i++) acc = fmaf(w5r[i], p.f5T[o5r[i] + c], acc);
      outp[512 + c] = acc;
      ls += acc; ls2 = fmaf(acc, acc, ls2);
    }
    for (int off = 32; off; off >>= 1) {
      ls += __shfl_down(ls, off);
      ls2 += __shfl_down(ls2, off);
    }
    int wv = t >> 6;
    if ((t & 63) == 0) { sh.red[wv] = ls; sh.red[4 + wv] = ls2; }
    __syncthreads();
    if (t == 0) {
      atomicAdd(&p.stats[bg * 2 + 0], sh.red[0] + sh.red[1] + sh.red[2] + sh.red[3]);
      atomicAdd(&p.stats[bg * 2 + 1], sh.red[4] + sh.red[5] + sh.red[6] + sh.red[7]);
    }
  }
}

__global__ __launch_bounds__(256, 4) void k_phase3(Params p) {
  // LN1 apply + ReLU -> sknT bf16 [r][k], k = c*25+pp. Coalesced via LDS transpose.
  __shared__ Sh3 sh;
  int bid = blockIdx.x, t = threadIdx.x, gb = gridDim.x;
  for (int u = bid; u < 384; u += gb) {
    __syncthreads();
    int r = u / 6, ch = u - r * 6;
    int c0 = ch * 256;
    float S = p.stats[r * 2], S2 = p.stats[r * 2 + 1];
    float mu = S * (1.f / D1);
    float var = S2 * (1.f / D1) - mu * mu;
    float rs = rsqrtf(var + 1e-5f);
    const float* rp = p.roisP + (size_t)r * 25 * CAPP + c0;
#pragma unroll
    for (int pp = 0; pp < 25; pp++)
      sh.tile[pp * 257 + t] = rp[(size_t)pp * CAPP + t];
    __syncthreads();
    unsigned short* op = p.sknT + (size_t)r * D1 + c0 * 25;
    const float* wv = p.n1w + c0 * 25;
    const float* bv = p.n1b + c0 * 25;
    for (int j = t; j < 6400; j += 256) {
      unsigned cc = (unsigned)j / 25u;
      unsigned pp = (unsigned)j - cc * 25u;
      float x = sh.tile[pp * 257 + cc];
      float v = fmaf((x - mu) * rs, wv[j], bv[j]);
      op[j] = f2bf(fmaxf(v, 0.f));
    }
  }
}

__global__ __launch_bounds__(256, 4) void k_phase4(Params p) {
  // fc1: 8 ntiles x 120 k-splits of 320, atomic into out1 (best config).
  // XCD-chunked (960 = 8*120).
  __shared__ GemmSh sh;
  int bid = blockIdx.x, gb = gridDim.x;
  for (int uu = bid; uu < 960; uu += gb) {
    int u = (uu & 7) * 120 + (uu >> 3);
    __syncthreads();
    int nt = u & 7, sp = u >> 3;
    gemm_unit<false>(sh, p.sknT, p.fw1, p.out1, 0, nt, sp * 320, 320, 38400, 512, 64, true);
  }
}

__global__ __launch_bounds__(256, 4) void k_phase5(Params p) {
  // LN2 + fc2 from out1 (fc1 atomics) + fb1.
  __shared__ Sh5 sh;
  int bid = blockIdx.x, t = threadIdx.x, gb = gridDim.x;
  for (int r = bid; r < NR; r += gb) {
    __syncthreads();
    int j1 = t, j2 = t + 256;
    float v1 = p.out1[r * 512 + j1] + p.fb1[j1];
    float v2 = p.out1[r * 512 + j2] + p.fb1[j2];
    float s = v1 + v2, s2 = v1 * v1 + v2 * v2;
    for (int off = 32; off; off >>= 1) {
      s += __shfl_down(s, off);
      s2 += __shfl_down(s2, off);
    }
    int wv = t >> 6;
    if ((t & 63) == 0) { sh.red[wv] = s; sh.red[4 + wv] = s2; }
    __syncthreads();
    float S = sh.red[0] + sh.red[1] + sh.red[2] + sh.red[3];
    float S2 = sh.red[4] + sh.red[5] + sh.red[6] + sh.red[7];
    float mu = S / 512.f;
    float var = S2 / 512.f - mu * mu;
    float rs = rsqrtf(var + 1e-5f);
    float n1v = fmaf((v1 - mu) * rs, p.n2w[j1], p.n2b[j1]);
    float n2v = fmaf((v2 - mu) * rs, p.n2w[j2], p.n2b[j2]);
    float pm[6];
#pragma unroll
    for (int m = 0; m < 6; m++)
      pm[m] = n1v * p.fw2[m * 512 + j1] + n2v * p.fw2[m * 512 + j2];
#pragma unroll
    for (int m = 0; m < 6; m++)
      for (int off = 32; off; off >>= 1) pm[m] += __shfl_down(pm[m], off);
    if ((t & 63) == 0) {
#pragma unroll
      for (int m = 0; m < 6; m++) sh.red2[wv * 6 + m] = pm[m];
    }
    __syncthreads();
    if (t < 6)
      p.out[r * 6 + t] = sh.red2[t] + sh.red2[6 + t] + sh.red2[12 + t] +
                         sh.red2[18 + t] + p.fb2[t];
  }
}

extern "C" void kernel_launch(void* const* d_in, const int* in_sizes, int n_in,
                              void* d_out, int out_size, void* d_ws, size_t ws_size,
                              hipStream_t stream) {
  Params p;
  p.x4    = (const float*)d_in[0];
  p.x5    = (const float*)d_in[1];
  p.boxes = (const float*)d_in[2];
  p.skel  = (const float*)d_in[3];
  p.group = (const int*)d_in[4];
  p.label = (const int*)d_in[6];
  p.c1w   = (const float*)d_in[7];
  p.c1b   = (const float*)d_in[8];
  p.w2c   = (const float*)d_in[9];
  p.b2c   = (const float*)d_in[10];
  p.w3c   = (const float*)d_in[11];
  p.b3c   = (const float*)d_in[12];
  p.n1w   = (const float*)d_in[13];
  p.n1b   = (const float*)d_in[14];
  p.n2w   = (const float*)d_in[15];
  p.n2b   = (const float*)d_in[16];
  p.fw1   = (const float*)d_in[17];
  p.fb1   = (const float*)d_in[18];
  p.fw2   = (const float*)d_in[19];
  p.fb2   = (const float*)d_in[20];
  p.out   = (float*)d_out;

  // workspace layout — ALL offsets in FLOAT units.
  float* ws = (float*)d_ws;
  p.x4T   = (unsigned short*)ws;              // 1600*1024 sh = 819200 f
  p.x5T   = (unsigned short*)(ws + 819200);   // 448*2048 sh  = 458752 f
  p.f4T   = ws + 1277952;                     // 1600*512  = 819,200 (1568 valid)
  p.f5T   = ws + 2097152;                     // 448*1024  = 458,752 (392 valid)
  p.tap4w = ws + 2555904;                     // 3136
  p.tap4o = (int*)(ws + 2559040);             // 3136
  p.tap5w = ws + 2562176;                     // 3136
  p.tap5o = (int*)(ws + 2565312);             // 3136
  p.descw = ws + 2568448;                     // 6400
  p.desco = (int*)(ws + 2574848);             // 6400
  p.roisP = ws + 2581248;                     // 64*25*1536 = 2,457,600
  p.stats = ws + 5038848;                     // 128 (raw S, S2 per row)
  p.sknT  = (unsigned short*)(ws + 5038976);  // 64*38400 sh = 1,228,800 f
  p.out1  = ws + 6267776;                     // 64*512 = 32,768
  p.w2cH  = (unsigned short*)(ws + 6300544);  // 524,288 sh = 262,144 f
  p.w3cH  = (unsigned short*)(ws + 6562688);  // 2,097,152 sh = 1,048,576 f (end 7,611,264 f)

  k_phase0<<<836,  256, 0, stream>>>(p);
  k_phase1<<<1696, 256, 0, stream>>>(p);
  k_phase2<<<1600, 256, 0, stream>>>(p);
  k_phase3<<<384,  256, 0, stream>>>(p);
  k_phase4<<<960,  256, 0, stream>>>(p);
  k_phase5<<<64,   256, 0, stream>>>(p);
}